// Round 9
// baseline (193.825 us; speedup 1.0000x reference)
//
#include <hip/hip_runtime.h>
#include <math.h>

#define RPOOL 5
#define NREP  8   // PROBE: 8 identical in-kernel repetitions (idempotent output)

__global__ __launch_bounds__(256, 4)
void minmax_pool_sort_kernel(const float* __restrict__ x,
                             const int* __restrict__ lengths,
                             float* __restrict__ out,
                             int n, int L) {
    const int lane = threadIdx.x & 63;
    const int row = __builtin_amdgcn_readfirstlane(blockIdx.x * 4 + (threadIdx.x >> 6));
    if (row >= n) return;

    int zero = 0;  // runtime-0, opaque to the compiler after each asm below

    for (int rep = 0; rep < NREP; ++rep) {
        // Opaque redefinition: prevents LICM/CSE collapsing the 8 reps.
        asm volatile("" : "+s"(zero));

        const int l = __builtin_amdgcn_readfirstlane(lengths[row + zero]);
        const float* xr = x + (long long)(row + zero) * L;

        int s[RPOOL], e[RPOOL];
#pragma unroll
        for (int j = 0; j < RPOOL; ++j) {
            s[j] = (j * l) / RPOOL;                      // floor(j*l/R)
            e[j] = ((j + 1) * l + RPOOL - 1) / RPOOL;    // ceil((j+1)*l/R)
        }

        float4 v[RPOOL];
        int    t0[RPOOL];
#pragma unroll
        for (int j = 0; j < RPOOL; ++j) {
            const int sa = s[j] & ~3;            // 16B-aligned start
            const int t  = sa + lane * 4;
            t0[j] = t;
            const int idx = (t < e[j]) ? t : 0;  // clamp OOB lanes into the row
            v[j] = *reinterpret_cast<const float4*>(xr + idx);
        }

        float mx[RPOOL], mn[RPOOL];
#pragma unroll
        for (int j = 0; j < RPOOL; ++j) {
            const float vv0 = v[j].x, vv1 = v[j].y, vv2 = v[j].z, vv3 = v[j].w;
            const int t = t0[j];
            const bool ok0 = (t     >= s[j]) & (t     < e[j]);
            const bool ok1 = (t + 1 >= s[j]) & (t + 1 < e[j]);
            const bool ok2 = (t + 2 >= s[j]) & (t + 2 < e[j]);
            const bool ok3 = (t + 3 >= s[j]) & (t + 3 < e[j]);
            const float m0 = ok0 ? vv0 : -INFINITY, n0 = ok0 ? vv0 : INFINITY;
            const float m1 = ok1 ? vv1 : -INFINITY, n1 = ok1 ? vv1 : INFINITY;
            const float m2 = ok2 ? vv2 : -INFINITY, n2 = ok2 ? vv2 : INFINITY;
            const float m3 = ok3 ? vv3 : -INFINITY, n3 = ok3 ? vv3 : INFINITY;
            mx[j] = fmaxf(fmaxf(m0, m1), fmaxf(m2, m3));
            mn[j] = fminf(fminf(n0, n1), fminf(n2, n3));
        }

#pragma unroll
        for (int off = 32; off > 0; off >>= 1) {
#pragma unroll
            for (int j = 0; j < RPOOL; ++j) {
                mx[j] = fmaxf(mx[j], __shfl_xor(mx[j], off, 64));
                mn[j] = fminf(mn[j], __shfl_xor(mn[j], off, 64));
            }
        }

        float vals[2 * RPOOL];
#pragma unroll
        for (int j = 0; j < RPOOL; ++j) { vals[j] = mx[j]; vals[RPOOL + j] = mn[j]; }

#pragma unroll
        for (int i = 0; i < 2 * RPOOL - 1; ++i) {
#pragma unroll
            for (int k = 0; k < 2 * RPOOL - 1 - i; ++k) {
                const float a = vals[k];
                const float b = vals[k + 1];
                vals[k]     = fminf(a, b);
                vals[k + 1] = fmaxf(a, b);
            }
        }

        float ov = vals[0];
#pragma unroll
        for (int k = 1; k < 2 * RPOOL; ++k) ov = (lane == k) ? vals[k] : ov;
        if (lane < 2 * RPOOL) out[(long long)row * (2 * RPOOL) + lane] = ov;
    }
}

extern "C" void kernel_launch(void* const* d_in, const int* in_sizes, int n_in,
                              void* d_out, int out_size, void* d_ws, size_t ws_size,
                              hipStream_t stream) {
    const float* x       = (const float*)d_in[0];
    const int*   lengths = (const int*)d_in[1];
    float*       out     = (float*)d_out;

    const int n = in_sizes[1];            // N rows
    const int L = in_sizes[0] / n;        // row stride (1000)

    const int blocks = (n + 3) / 4;       // 4 waves (rows) per 256-thread block
    hipLaunchKernelGGL(minmax_pool_sort_kernel, dim3(blocks), dim3(256), 0, stream,
                       x, lengths, out, n, L);
}

// Round 12
// 23.752 us; speedup vs baseline: 8.1604x; 8.1604x over previous
//
#include <hip/hip_runtime.h>
#include <math.h>

#define RPOOL 5

// 4-byte-aligned float4: gfx950 global loads support dword-aligned dwordx4.
typedef float float4u __attribute__((ext_vector_type(4), aligned(4)));
// Native packed-fp16 vector, matching __builtin_amdgcn_cvt_pkrtz's return
// type (__fp16 ext_vector_type(2)). __builtin_elementwise_max on it lowers
// to v_pk_max_f16.
typedef __fp16 half2v __attribute__((ext_vector_type(2)));

__global__ __launch_bounds__(256, 4)
void minmax_pool_sort_kernel(const float* __restrict__ x,
                             const int* __restrict__ lengths,
                             float* __restrict__ out,
                             int n, int L) {
    const int lane = threadIdx.x & 63;
    const int row = __builtin_amdgcn_readfirstlane(blockIdx.x * 4 + (threadIdx.x >> 6));
    if (row >= n) return;

    const int l = __builtin_amdgcn_readfirstlane(lengths[row]);
    const float* xr = x + (long long)row * L;
    const int lane4 = lane * 4;

    float vals[2 * RPOOL];

    if (l >= 4 * RPOOL) {
        // ---------- FAST PATH (l >= 20): mask-free clamp-loads ----------
        // Window j = [s, e), size >= 4. Load float4 at idx = min(s+4*lane, e-4):
        // all 4 elements are inside [s, e) (duplicates harmless for max/min),
        // and every window element is covered (clamped lanes read (e-4..e)).
        half2v pk[RPOOL];
#pragma unroll
        for (int j = 0; j < RPOOL; ++j) {
            const int s = (j * l) / RPOOL;                     // floor(j*l/R)
            const int e = ((j + 1) * l + RPOOL - 1) / RPOOL;   // ceil((j+1)*l/R)
            int idx = s + lane4;
            idx = (idx < e - 4) ? idx : (e - 4);
            const float4u v = *reinterpret_cast<const float4u*>(xr + idx);
            const float mx = fmaxf(fmaxf(v.x, v.y), fmaxf(v.z, v.w));
            const float mn = fminf(fminf(v.x, v.y), fminf(v.z, v.w));
            // Pack (max, -min) -> one packed max butterfly reduces both.
            pk[j] = __builtin_amdgcn_cvt_pkrtz(mx, -mn);
        }

        // Butterfly on packed fp16: one shuffle + one v_pk_max_f16 per level.
#pragma unroll
        for (int off = 32; off > 0; off >>= 1) {
#pragma unroll
            for (int j = 0; j < RPOOL; ++j) {
                int pi;
                __builtin_memcpy(&pi, &pk[j], 4);
                const int qi = __shfl_xor(pi, off, 64);
                half2v q;
                __builtin_memcpy(&q, &qi, 4);
                pk[j] = __builtin_elementwise_max(pk[j], q);
            }
        }

#pragma unroll
        for (int j = 0; j < RPOOL; ++j) {
            vals[j]         =  (float)pk[j][0];   // max
            vals[RPOOL + j] = -(float)pk[j][1];   // min = -max(-x)
        }
    } else {
        // ---------- SLOW PATH (l < 20, ~1.5% of rows): exact masked f32 ----------
        int s[RPOOL], e[RPOOL];
#pragma unroll
        for (int j = 0; j < RPOOL; ++j) {
            s[j] = (j * l) / RPOOL;
            e[j] = ((j + 1) * l + RPOOL - 1) / RPOOL;
        }
        float mx[RPOOL], mn[RPOOL];
#pragma unroll
        for (int j = 0; j < RPOOL; ++j) {
            const int sa = s[j] & ~3;
            const int t  = sa + lane4;
            const int idx = (t < e[j]) ? t : 0;
            const float4u v = *reinterpret_cast<const float4u*>(xr + idx);
            const bool ok0 = (t     >= s[j]) & (t     < e[j]);
            const bool ok1 = (t + 1 >= s[j]) & (t + 1 < e[j]);
            const bool ok2 = (t + 2 >= s[j]) & (t + 2 < e[j]);
            const bool ok3 = (t + 3 >= s[j]) & (t + 3 < e[j]);
            const float m0 = ok0 ? v.x : -INFINITY, n0 = ok0 ? v.x : INFINITY;
            const float m1 = ok1 ? v.y : -INFINITY, n1 = ok1 ? v.y : INFINITY;
            const float m2 = ok2 ? v.z : -INFINITY, n2 = ok2 ? v.z : INFINITY;
            const float m3 = ok3 ? v.w : -INFINITY, n3 = ok3 ? v.w : INFINITY;
            mx[j] = fmaxf(fmaxf(m0, m1), fmaxf(m2, m3));
            mn[j] = fminf(fminf(n0, n1), fminf(n2, n3));
        }
#pragma unroll
        for (int off = 32; off > 0; off >>= 1) {
#pragma unroll
            for (int j = 0; j < RPOOL; ++j) {
                mx[j] = fmaxf(mx[j], __shfl_xor(mx[j], off, 64));
                mn[j] = fminf(mn[j], __shfl_xor(mn[j], off, 64));
            }
        }
#pragma unroll
        for (int j = 0; j < RPOOL; ++j) { vals[j] = mx[j]; vals[RPOOL + j] = mn[j]; }
    }

    // Sort 10 ascending — fully-unrolled bubble network (known correct).
#pragma unroll
    for (int i = 0; i < 2 * RPOOL - 1; ++i) {
#pragma unroll
        for (int k = 0; k < 2 * RPOOL - 1 - i; ++k) {
            const float a = vals[k];
            const float b = vals[k + 1];
            vals[k]     = fminf(a, b);
            vals[k + 1] = fmaxf(a, b);
        }
    }

    // Coalesced store: lanes 0..9 store one value each.
    float ov = vals[0];
#pragma unroll
    for (int k = 1; k < 2 * RPOOL; ++k) ov = (lane == k) ? vals[k] : ov;
    if (lane < 2 * RPOOL) out[(long long)row * (2 * RPOOL) + lane] = ov;
}

extern "C" void kernel_launch(void* const* d_in, const int* in_sizes, int n_in,
                              void* d_out, int out_size, void* d_ws, size_t ws_size,
                              hipStream_t stream) {
    const float* x       = (const float*)d_in[0];
    const int*   lengths = (const int*)d_in[1];
    float*       out     = (float*)d_out;

    const int n = in_sizes[1];            // N rows
    const int L = in_sizes[0] / n;        // row stride (1000)

    const int blocks = (n + 3) / 4;       // 4 waves (rows) per 256-thread block
    hipLaunchKernelGGL(minmax_pool_sort_kernel, dim3(blocks), dim3(256), 0, stream,
                       x, lengths, out, n, L);
}

// Round 13
// 18.474 us; speedup vs baseline: 10.4918x; 1.2857x over previous
//
#include <hip/hip_runtime.h>
#include <math.h>

#define RPOOL 5

// 4-byte-aligned float4: gfx950 global loads support dword-aligned dwordx4.
typedef float float4u __attribute__((ext_vector_type(4), aligned(4)));

template <int CTRL>
__device__ __forceinline__ float dpp_mov(float v) {
    const int iv = __float_as_int(v);
    const int o  = __builtin_amdgcn_update_dpp(iv, iv, CTRL, 0xf, 0xf, false);
    return __int_as_float(o);
}

// 16-lane-group butterfly (masks {1,2,7,15} span GF(2)^4; max/min idempotent
// so every lane of the group ends with the group reduce). All intra-row DPP:
// v_max_f32 is VOP2 -> backend fuses the dpp mov into the max operand.
__device__ __forceinline__ float grp_fmax(float v) {
    v = fmaxf(v, dpp_mov<0xB1>(v));    // quad_perm [1,0,3,2] : xor 1
    v = fmaxf(v, dpp_mov<0x4E>(v));    // quad_perm [2,3,0,1] : xor 2
    v = fmaxf(v, dpp_mov<0x141>(v));   // row_half_mirror     : xor 7
    v = fmaxf(v, dpp_mov<0x140>(v));   // row_mirror          : xor 15
    return v;
}
__device__ __forceinline__ float grp_fmin(float v) {
    v = fminf(v, dpp_mov<0xB1>(v));
    v = fminf(v, dpp_mov<0x4E>(v));
    v = fminf(v, dpp_mov<0x141>(v));
    v = fminf(v, dpp_mov<0x140>(v));
    return v;
}

__global__ __launch_bounds__(256, 8)
void minmax_pool_sort_kernel(const float* __restrict__ x,
                             const int* __restrict__ lengths,
                             float* __restrict__ out,
                             int n, int L) {
    // 16 lanes per row: block of 256 handles 16 rows (4 rows per wave).
    const int sub = threadIdx.x & 15;
    const int row = blockIdx.x * 16 + (threadIdx.x >> 4);
    if (row >= n) return;

    const int lv = lengths[row];                  // per-lane (per-group) length
    const float* xr = x + (long long)row * L;
    const int sub4 = sub * 4;

    float mx[RPOOL], mn[RPOOL];

    if (!__any(lv < 4 * RPOOL)) {
        // ---------- FAST PATH (all 4 rows have l >= 20): mask-free clamp-loads ----
        // Window j = [s,e), size >= 4. Sub-load k covers raw [s+64k+4*sub, +4);
        // clamp idx to e-4 keeps every element in [s,e) (dups harmless) and the
        // clamped loads cover the tail. 4 sub-loads cover size <= 256 >= 201 max.
#pragma unroll
        for (int j = 0; j < RPOOL; ++j) {
            const int s   = (j * lv) / RPOOL;                    // floor(j*l/R)
            const int e   = ((j + 1) * lv + RPOOL - 1) / RPOOL;  // ceil((j+1)*l/R)
            const int cap = e - 4;
            float mxw = -INFINITY, mnw = INFINITY;
#pragma unroll
            for (int k = 0; k < 4; ++k) {
                int idx = s + sub4 + k * 64;
                idx = (idx < cap) ? idx : cap;
                const float4u v = *reinterpret_cast<const float4u*>(xr + idx);
                mxw = fmaxf(mxw, fmaxf(fmaxf(v.x, v.y), fmaxf(v.z, v.w)));
                mnw = fminf(mnw, fminf(fminf(v.x, v.y), fminf(v.z, v.w)));
            }
            mx[j] = grp_fmax(mxw);
            mn[j] = grp_fmin(mnw);
        }
    } else {
        // ---------- SLOW PATH (~6% of waves): exact masked loads, any l >= 1 ----
#pragma unroll
        for (int j = 0; j < RPOOL; ++j) {
            const int s  = (j * lv) / RPOOL;
            const int e  = ((j + 1) * lv + RPOOL - 1) / RPOOL;
            const int sa = s & ~3;                 // aligned head
            float mxw = -INFINITY, mnw = INFINITY;
#pragma unroll
            for (int k = 0; k < 4; ++k) {
                const int t = sa + sub4 + k * 64;
                const int idx = (t < e) ? t : 0;   // clamp into row; masked below
                const float4u v = *reinterpret_cast<const float4u*>(xr + idx);
                const bool ok0 = (t     >= s) & (t     < e);
                const bool ok1 = (t + 1 >= s) & (t + 1 < e);
                const bool ok2 = (t + 2 >= s) & (t + 2 < e);
                const bool ok3 = (t + 3 >= s) & (t + 3 < e);
                mxw = fmaxf(mxw, ok0 ? v.x : -INFINITY);
                mxw = fmaxf(mxw, ok1 ? v.y : -INFINITY);
                mxw = fmaxf(mxw, ok2 ? v.z : -INFINITY);
                mxw = fmaxf(mxw, ok3 ? v.w : -INFINITY);
                mnw = fminf(mnw, ok0 ? v.x :  INFINITY);
                mnw = fminf(mnw, ok1 ? v.y :  INFINITY);
                mnw = fminf(mnw, ok2 ? v.z :  INFINITY);
                mnw = fminf(mnw, ok3 ? v.w :  INFINITY);
            }
            mx[j] = grp_fmax(mxw);
            mn[j] = grp_fmin(mnw);
        }
    }

    float vals[2 * RPOOL];
#pragma unroll
    for (int j = 0; j < RPOOL; ++j) { vals[j] = mx[j]; vals[RPOOL + j] = mn[j]; }

    // Sort 10 ascending — fully-unrolled bubble network (known correct).
    // Shared by all 4 rows of the wave (amortized 4x).
#pragma unroll
    for (int i = 0; i < 2 * RPOOL - 1; ++i) {
#pragma unroll
        for (int k = 0; k < 2 * RPOOL - 1 - i; ++k) {
            const float a = vals[k];
            const float b = vals[k + 1];
            vals[k]     = fminf(a, b);
            vals[k + 1] = fmaxf(a, b);
        }
    }

    // Store: lanes 0..9 of each 16-lane group store their row's 10 values.
    float ov = vals[0];
#pragma unroll
    for (int k = 1; k < 2 * RPOOL; ++k) ov = (sub == k) ? vals[k] : ov;
    if (sub < 2 * RPOOL) out[(long long)row * (2 * RPOOL) + sub] = ov;
}

extern "C" void kernel_launch(void* const* d_in, const int* in_sizes, int n_in,
                              void* d_out, int out_size, void* d_ws, size_t ws_size,
                              hipStream_t stream) {
    const float* x       = (const float*)d_in[0];
    const int*   lengths = (const int*)d_in[1];
    float*       out     = (float*)d_out;

    const int n = in_sizes[1];            // N rows
    const int L = in_sizes[0] / n;        // row stride (1000)

    const int blocks = (n + 15) / 16;     // 16 rows per 256-thread block
    hipLaunchKernelGGL(minmax_pool_sort_kernel, dim3(blocks), dim3(256), 0, stream,
                       x, lengths, out, n, L);
}